// Round 2
// baseline (3526.702 us; speedup 1.0000x reference)
//
#include <hip/hip_runtime.h>

#define N_NODES 50000
#define N_EDGES 500000
#define F_INDIM 388
#define H_HEADS 8
#define DD1 64
#define DD2 128
#define EDIM 16
#define HIDN 32

typedef unsigned short u16;

static __device__ __forceinline__ float bfu2f(unsigned int lo16) {
  union { unsigned int u; float f; } c;
  c.u = lo16 << 16;
  return c.f;
}
static __device__ __forceinline__ u16 f2bf(float f) {
  union { float f; unsigned int u; } c;
  c.f = f;
  unsigned int u = c.u + 0x7fffu + ((c.u >> 16) & 1u);
  return (u16)(u >> 16);
}

static __device__ __forceinline__ float waveSum(float v) {
#pragma unroll
  for (int off = 32; off > 0; off >>= 1) v += __shfl_xor(v, off, 64);
  return v;
}

__global__ void k_zero(float* __restrict__ out, int n) {
  int i = blockIdx.x * blockDim.x + threadIdx.x;
  if (i < n) out[i] = 0.f;
}

// ---------------- CSR build ----------------
__global__ void k_hist(const int* __restrict__ dst, int* __restrict__ deg) {
  int e = blockIdx.x * blockDim.x + threadIdx.x;
  if (e < N_EDGES) atomicAdd(&deg[dst[e]], 1);
}

__global__ __launch_bounds__(1024) void k_scan(const int* __restrict__ deg,
                                               int* __restrict__ row_start) {
  __shared__ int wsum[16];
  __shared__ int carry_s;
  int tid = threadIdx.x;
  int lane = tid & 63, wv = tid >> 6;
  if (tid == 0) carry_s = 0;
  __syncthreads();
  for (int base = 0; base < N_NODES; base += 1024) {
    int i = base + tid;
    int v = (i < N_NODES) ? deg[i] : 0;
    int inc = v;
#pragma unroll
    for (int off = 1; off < 64; off <<= 1) {
      int t = __shfl_up(inc, off, 64);
      if (lane >= off) inc += t;
    }
    if (lane == 63) wsum[wv] = inc;
    __syncthreads();
    if (wv == 0 && lane < 16) {
      int s = wsum[lane];
#pragma unroll
      for (int off = 1; off < 16; off <<= 1) {
        int t = __shfl_up(s, off, 64);
        if (lane >= off) s += t;
      }
      wsum[lane] = s;
    }
    __syncthreads();
    int add = (wv > 0) ? wsum[wv - 1] : 0;
    int ex = carry_s + add + inc - v;
    if (i < N_NODES) row_start[i] = ex;
    __syncthreads();
    if (tid == 0) carry_s += wsum[15];
    __syncthreads();
  }
  if (threadIdx.x == 0) row_start[N_NODES] = carry_s;
}

__global__ void k_scatter(const int* __restrict__ dst, const int* __restrict__ row_start,
                          int* __restrict__ cursor, int* __restrict__ eid) {
  int e = blockIdx.x * blockDim.x + threadIdx.x;
  if (e < N_EDGES) {
    int d = dst[e];
    int pos = row_start[d] + atomicAdd(&cursor[d], 1);
    eid[pos] = e;
  }
}

// ---------------- GEMM: C[M,N](bf16) = A[M,K] @ B[K,N](f32) ----------------
// ABF16=false: A fp32.  ABF16=true: A bf16 (K must be mult of 16).
template <bool ABF16>
__global__ __launch_bounds__(256) void gemm_cbf16(const void* __restrict__ Av,
                                                  const float* __restrict__ B,
                                                  u16* __restrict__ C, int M, int K, int Nd) {
  __shared__ float As[16][128];
  __shared__ float Bs[16][64];
  int tid = threadIdx.x;
  int tx = tid & 15;   // n group (n0 = tx*4)
  int ty = tid >> 4;   // m group (m0 = ty*8)
  int m_base = blockIdx.y * 128;
  int n_base = blockIdx.x * 64;
  float acc[8][4];
#pragma unroll
  for (int i = 0; i < 8; ++i)
#pragma unroll
    for (int j = 0; j < 4; ++j) acc[i][j] = 0.f;

  for (int k0 = 0; k0 < K; k0 += 16) {
    if (ABF16) {
      const u16* A = (const u16*)Av;
      int row = tid >> 1;
      int c8 = (tid & 1) * 8;
      int gm = m_base + row;
      uint4 v = make_uint4(0, 0, 0, 0);
      if (gm < M) v = *(const uint4*)(A + (size_t)gm * K + k0 + c8);
      As[c8 + 0][row] = bfu2f(v.x & 0xffff);
      As[c8 + 1][row] = bfu2f(v.x >> 16);
      As[c8 + 2][row] = bfu2f(v.y & 0xffff);
      As[c8 + 3][row] = bfu2f(v.y >> 16);
      As[c8 + 4][row] = bfu2f(v.z & 0xffff);
      As[c8 + 5][row] = bfu2f(v.z >> 16);
      As[c8 + 6][row] = bfu2f(v.w & 0xffff);
      As[c8 + 7][row] = bfu2f(v.w >> 16);
    } else {
      const float* A = (const float*)Av;
#pragma unroll
      for (int r = 0; r < 2; ++r) {
        int t = tid + r * 256;
        int row = t >> 2;
        int c4 = (t & 3) * 4;
        int gm = m_base + row;
        int gk = k0 + c4;
        float4 v = make_float4(0.f, 0.f, 0.f, 0.f);
        if (gm < M && gk < K) v = *(const float4*)(A + (size_t)gm * K + gk);
        As[c4 + 0][row] = v.x;
        As[c4 + 1][row] = v.y;
        As[c4 + 2][row] = v.z;
        As[c4 + 3][row] = v.w;
      }
    }
    {
      int r = tid >> 4;
      int c4 = (tid & 15) * 4;
      int gk = k0 + r;
      float4 v = make_float4(0.f, 0.f, 0.f, 0.f);
      if (gk < K) v = *(const float4*)(B + (size_t)gk * Nd + n_base + c4);
      *(float4*)&Bs[r][c4] = v;
    }
    __syncthreads();
#pragma unroll
    for (int k = 0; k < 16; ++k) {
      float4 b4 = *(const float4*)&Bs[k][tx * 4];
      float4 a0 = *(const float4*)&As[k][ty * 8];
      float4 a1 = *(const float4*)&As[k][ty * 8 + 4];
      float a[8] = {a0.x, a0.y, a0.z, a0.w, a1.x, a1.y, a1.z, a1.w};
      float b[4] = {b4.x, b4.y, b4.z, b4.w};
#pragma unroll
      for (int i = 0; i < 8; ++i)
#pragma unroll
        for (int j = 0; j < 4; ++j) acc[i][j] = fmaf(a[i], b[j], acc[i][j]);
    }
    __syncthreads();
  }
#pragma unroll
  for (int i = 0; i < 8; ++i) {
    int gm = m_base + ty * 8 + i;
    if (gm < M) {
      ushort4 o;
      o.x = f2bf(acc[i][0]);
      o.y = f2bf(acc[i][1]);
      o.z = f2bf(acc[i][2]);
      o.w = f2bf(acc[i][3]);
      *(ushort4*)(C + (size_t)gm * Nd + n_base + tx * 4) = o;
    }
  }
}

// ---------------- fp32 GEMM, B transposed: C[M,N] = A[M,K] @ B^T, B[N,K] ----------------
__global__ __launch_bounds__(256) void gemm_f32_tb(const float* __restrict__ A,
                                                   const float* __restrict__ B,
                                                   float* __restrict__ C, int M, int K, int Nd) {
  __shared__ float As[16][128];
  __shared__ float Bs[16][64];
  int tid = threadIdx.x;
  int tx = tid & 15;
  int ty = tid >> 4;
  int m_base = blockIdx.y * 128;
  int n_base = blockIdx.x * 64;
  float acc[8][4];
#pragma unroll
  for (int i = 0; i < 8; ++i)
#pragma unroll
    for (int j = 0; j < 4; ++j) acc[i][j] = 0.f;

  for (int k0 = 0; k0 < K; k0 += 16) {
#pragma unroll
    for (int r = 0; r < 2; ++r) {
      int t = tid + r * 256;
      int row = t >> 2;
      int c4 = (t & 3) * 4;
      int gm = m_base + row;
      int gk = k0 + c4;
      float4 v = make_float4(0.f, 0.f, 0.f, 0.f);
      if (gm < M && gk < K) v = *(const float4*)(A + (size_t)gm * K + gk);
      As[c4 + 0][row] = v.x;
      As[c4 + 1][row] = v.y;
      As[c4 + 2][row] = v.z;
      As[c4 + 3][row] = v.w;
    }
    {
      int c = tid >> 2;
      int r4 = (tid & 3) * 4;
      int gk = k0 + r4;
      float4 v = make_float4(0.f, 0.f, 0.f, 0.f);
      if (gk < K) v = *(const float4*)(B + (size_t)(n_base + c) * K + gk);
      Bs[r4 + 0][c] = v.x;
      Bs[r4 + 1][c] = v.y;
      Bs[r4 + 2][c] = v.z;
      Bs[r4 + 3][c] = v.w;
    }
    __syncthreads();
#pragma unroll
    for (int k = 0; k < 16; ++k) {
      float4 b4 = *(const float4*)&Bs[k][tx * 4];
      float4 a0 = *(const float4*)&As[k][ty * 8];
      float4 a1 = *(const float4*)&As[k][ty * 8 + 4];
      float a[8] = {a0.x, a0.y, a0.z, a0.w, a1.x, a1.y, a1.z, a1.w};
      float b[4] = {b4.x, b4.y, b4.z, b4.w};
#pragma unroll
      for (int i = 0; i < 8; ++i)
#pragma unroll
        for (int j = 0; j < 4; ++j) acc[i][j] = fmaf(a[i], b[j], acc[i][j]);
    }
    __syncthreads();
  }
#pragma unroll
  for (int i = 0; i < 8; ++i) {
    int gm = m_base + ty * 8 + i;
    if (gm < M) {
      float4 v = make_float4(acc[i][0], acc[i][1], acc[i][2], acc[i][3]);
      *(float4*)(C + (size_t)gm * Nd + n_base + tx * 4) = v;
    }
  }
}

// ---------------- GAT layer 1 (D=64, concat) — bf16 xl/xr, bf16 out ----------------
__global__ __launch_bounds__(512) void k_gat1(
    const u16* __restrict__ xl, const u16* __restrict__ xr, const float* __restrict__ ea,
    const float* __restrict__ We, const float* __restrict__ att, const float* __restrict__ bias,
    const int* __restrict__ src, const int* __restrict__ eid, const int* __restrict__ row_start,
    u16* __restrict__ out) {
  const int NC = H_HEADS * DD1;  // 512
  int n = blockIdx.x;
  int lane = threadIdx.x & 63;
  int h = threadIdx.x >> 6;
  __shared__ float la[EDIM];
  int r0 = row_start[n], r1 = row_start[n + 1];
  if (threadIdx.x < EDIM) {
    float s = 0.f;
    for (int i = r0; i < r1; ++i) s += ea[(size_t)eid[i] * EDIM + threadIdx.x];
    la[threadIdx.x] = s / (float)max(r1 - r0, 1);
  }
  __syncthreads();
  int col = h * DD1 + lane;
  float Wc[EDIM];
#pragma unroll
  for (int k = 0; k < EDIM; ++k) Wc[k] = We[k * NC + col];
  float attd = att[col];
  float xrd = bfu2f(xr[(size_t)n * NC + col]);
  float xlself = bfu2f(xl[(size_t)n * NC + col]);
  float ee = 0.f;
#pragma unroll
  for (int k = 0; k < EDIM; ++k) ee = fmaf(la[k], Wc[k], ee);
  float z = xlself + xrd + ee;
  float m = z > 0.f ? z : 0.2f * z;
  float sc = waveSum(m * attd);
  float w = __expf(sc);
  float acc = w * xlself;
  float denom = w;
  for (int i = r0; i < r1; ++i) {
    int e = __builtin_amdgcn_readfirstlane(eid[i]);
    int s = __builtin_amdgcn_readfirstlane(src[e]);
    float xv = bfu2f(xl[(size_t)s * NC + col]);
    const float4* ea4 = (const float4*)(ea + (size_t)e * EDIM);
    float eacc = 0.f;
#pragma unroll
    for (int q = 0; q < 4; ++q) {
      float4 v = ea4[q];
      eacc = fmaf(v.x, Wc[q * 4 + 0], eacc);
      eacc = fmaf(v.y, Wc[q * 4 + 1], eacc);
      eacc = fmaf(v.z, Wc[q * 4 + 2], eacc);
      eacc = fmaf(v.w, Wc[q * 4 + 3], eacc);
    }
    float zz = xv + xrd + eacc;
    float mm = zz > 0.f ? zz : 0.2f * zz;
    float s2 = waveSum(mm * attd);
    float ww = __expf(s2);
    acc = fmaf(ww, xv, acc);
    denom += ww;
  }
  out[(size_t)n * NC + col] = f2bf(tanhf(acc / denom + bias[col]));
}

// ---------------- GAT layer 2 (D=128, mean heads) — bf16 xl/xr, fp32 out ----------------
__global__ __launch_bounds__(512) void k_gat2(
    const u16* __restrict__ xl, const u16* __restrict__ xr, const float* __restrict__ ea,
    const float* __restrict__ We, const float* __restrict__ att, const float* __restrict__ bias,
    const int* __restrict__ src, const int* __restrict__ eid, const int* __restrict__ row_start,
    float* __restrict__ out) {
  const int NC = H_HEADS * DD2;  // 1024
  int n = blockIdx.x;
  int lane = threadIdx.x & 63;
  int h = threadIdx.x >> 6;
  __shared__ float la[EDIM];
  __shared__ float hsum[H_HEADS][DD2];
  int r0 = row_start[n], r1 = row_start[n + 1];
  if (threadIdx.x < EDIM) {
    float s = 0.f;
    for (int i = r0; i < r1; ++i) s += ea[(size_t)eid[i] * EDIM + threadIdx.x];
    la[threadIdx.x] = s / (float)max(r1 - r0, 1);
  }
  __syncthreads();
  int col = h * DD2 + lane * 2;
  float2 Wc[EDIM];
#pragma unroll
  for (int k = 0; k < EDIM; ++k) Wc[k] = *(const float2*)(We + k * NC + col);
  float2 attd = *(const float2*)(att + col);
  unsigned int xru = *(const unsigned int*)(xr + (size_t)n * NC + col);
  unsigned int xlu = *(const unsigned int*)(xl + (size_t)n * NC + col);
  float xrdx = bfu2f(xru & 0xffff), xrdy = bfu2f(xru >> 16);
  float xlsx = bfu2f(xlu & 0xffff), xlsy = bfu2f(xlu >> 16);
  float eex = 0.f, eey = 0.f;
#pragma unroll
  for (int k = 0; k < EDIM; ++k) {
    eex = fmaf(la[k], Wc[k].x, eex);
    eey = fmaf(la[k], Wc[k].y, eey);
  }
  float zx = xlsx + xrdx + eex, zy = xlsy + xrdy + eey;
  float mx = zx > 0.f ? zx : 0.2f * zx, my = zy > 0.f ? zy : 0.2f * zy;
  float sc = waveSum(mx * attd.x + my * attd.y);
  float w = __expf(sc);
  float accx = w * xlsx, accy = w * xlsy, denom = w;
  for (int i = r0; i < r1; ++i) {
    int e = __builtin_amdgcn_readfirstlane(eid[i]);
    int s = __builtin_amdgcn_readfirstlane(src[e]);
    unsigned int xvu = *(const unsigned int*)(xl + (size_t)s * NC + col);
    float xvx = bfu2f(xvu & 0xffff), xvy = bfu2f(xvu >> 16);
    const float4* ea4 = (const float4*)(ea + (size_t)e * EDIM);
    float ex = 0.f, ey = 0.f;
#pragma unroll
    for (int q = 0; q < 4; ++q) {
      float4 v = ea4[q];
      ex = fmaf(v.x, Wc[q * 4 + 0].x, ex);
      ey = fmaf(v.x, Wc[q * 4 + 0].y, ey);
      ex = fmaf(v.y, Wc[q * 4 + 1].x, ex);
      ey = fmaf(v.y, Wc[q * 4 + 1].y, ey);
      ex = fmaf(v.z, Wc[q * 4 + 2].x, ex);
      ey = fmaf(v.z, Wc[q * 4 + 2].y, ey);
      ex = fmaf(v.w, Wc[q * 4 + 3].x, ex);
      ey = fmaf(v.w, Wc[q * 4 + 3].y, ey);
    }
    float zx2 = xvx + xrdx + ex, zy2 = xvy + xrdy + ey;
    float mx2 = zx2 > 0.f ? zx2 : 0.2f * zx2, my2 = zy2 > 0.f ? zy2 : 0.2f * zy2;
    float s2 = waveSum(mx2 * attd.x + my2 * attd.y);
    float ww = __expf(s2);
    accx = fmaf(ww, xvx, accx);
    accy = fmaf(ww, xvy, accy);
    denom += ww;
  }
  float inv = 1.f / denom;
  hsum[h][lane * 2] = accx * inv;
  hsum[h][lane * 2 + 1] = accy * inv;
  __syncthreads();
  if (threadIdx.x < DD2) {
    float s = 0.f;
#pragma unroll
    for (int hh = 0; hh < H_HEADS; ++hh) s += hsum[hh][threadIdx.x];
    out[(size_t)n * DD2 + threadIdx.x] = tanhf(s * 0.125f + bias[threadIdx.x]);
  }
}

// ---------------- LSTM (single step, h0=c0=0) + FC ----------------
__global__ __launch_bounds__(128) void k_lstm(const float* __restrict__ gates,
                                              const float* __restrict__ b_ih,
                                              const float* __restrict__ b_hh,
                                              const float* __restrict__ fcW,
                                              const float* __restrict__ fcb,
                                              float* __restrict__ out) {
  int n = blockIdx.x;
  int j = threadIdx.x;
  __shared__ float gs[128];
  gs[j] = gates[(size_t)n * 128 + j] + b_ih[j] + b_hh[j];
  __syncthreads();
  if (j < 32) {
    float iv = gs[j], gv = gs[64 + j], ov = gs[96 + j];
    float c = (1.f / (1.f + __expf(-iv))) * tanhf(gv);
    float hd = (1.f / (1.f + __expf(-ov))) * tanhf(c);
    float p = hd * fcW[j];
#pragma unroll
    for (int off = 16; off > 0; off >>= 1) p += __shfl_down(p, off, 32);
    if (j == 0) out[n] = p + fcb[0];
  }
}

extern "C" void kernel_launch(void* const* d_in, const int* in_sizes, int n_in, void* d_out,
                              int out_size, void* d_ws, size_t ws_size, hipStream_t stream) {
  const float* x = (const float*)d_in[0];
  const int* ei = (const int*)d_in[1];
  const float* ea = (const float*)d_in[2];
  const float* Wl1 = (const float*)d_in[3];
  const float* Wr1 = (const float*)d_in[4];
  const float* We1 = (const float*)d_in[5];
  const float* att1 = (const float*)d_in[6];
  const float* b1 = (const float*)d_in[7];
  const float* Wl2 = (const float*)d_in[8];
  const float* Wr2 = (const float*)d_in[9];
  const float* We2 = (const float*)d_in[10];
  const float* att2 = (const float*)d_in[11];
  const float* b2 = (const float*)d_in[12];
  const float* W_ih = (const float*)d_in[13];
  const float* b_ih = (const float*)d_in[15];
  const float* b_hh = (const float*)d_in[16];
  const float* fcW = (const float*)d_in[17];
  const float* fcb = (const float*)d_in[18];
  float* out = (float*)d_out;
  const int* srcA = ei;
  const int* dstA = ei + N_EDGES;

  char* ws = (char*)d_ws;
  size_t off = 0;
  auto take = [&](size_t bytes) -> char* {
    off = (off + 255) & ~(size_t)255;
    char* p = ws + off;
    off += bytes;
    return p;
  };
  int* deg = (int*)take((size_t)N_NODES * 4);
  int* cursor = (int*)take((size_t)N_NODES * 4);
  int* row_start = (int*)take((size_t)(N_NODES + 1) * 4);
  int* eid = (int*)take((size_t)N_EDGES * 4);
  char* regA = take((size_t)N_NODES * 1024 * 2);  // xl1|xr1 (bf16), later xl2 (bf16)
  char* regB = take((size_t)N_NODES * 512 * 2);   // h1 (bf16), later h2+gates (fp32)
  char* regC = take((size_t)N_NODES * 1024 * 2);  // xr2 (bf16)

  if (off > ws_size) {
    // workspace too small: fail gracefully (distinguishes from a kernel fault)
    k_zero<<<(out_size + 255) / 256, 256, 0, stream>>>(out, out_size);
    return;
  }

  u16* xl1 = (u16*)regA;
  u16* xr1 = (u16*)(regA + (size_t)N_NODES * 512 * 2);
  u16* h1 = (u16*)regB;
  u16* xl2 = (u16*)regA;
  u16* xr2 = (u16*)regC;
  float* h2 = (float*)regB;
  float* gates = (float*)(regB + (size_t)N_NODES * 128 * 4);

  hipMemsetAsync(deg, 0, (size_t)N_NODES * 4, stream);
  hipMemsetAsync(cursor, 0, (size_t)N_NODES * 4, stream);
  k_hist<<<(N_EDGES + 255) / 256, 256, 0, stream>>>(dstA, deg);
  k_scan<<<1, 1024, 0, stream>>>(deg, row_start);
  k_scatter<<<(N_EDGES + 255) / 256, 256, 0, stream>>>(dstA, row_start, cursor, eid);

  dim3 g1(512 / 64, (N_NODES + 127) / 128);
  gemm_cbf16<false><<<g1, 256, 0, stream>>>(x, Wl1, xl1, N_NODES, F_INDIM, 512);
  gemm_cbf16<false><<<g1, 256, 0, stream>>>(x, Wr1, xr1, N_NODES, F_INDIM, 512);
  k_gat1<<<N_NODES, 512, 0, stream>>>(xl1, xr1, ea, We1, att1, b1, srcA, eid, row_start, h1);

  dim3 g2(1024 / 64, (N_NODES + 127) / 128);
  gemm_cbf16<true><<<g2, 256, 0, stream>>>(h1, Wl2, xl2, N_NODES, 512, 1024);
  gemm_cbf16<true><<<g2, 256, 0, stream>>>(h1, Wr2, xr2, N_NODES, 512, 1024);
  k_gat2<<<N_NODES, 512, 0, stream>>>(xl2, xr2, ea, We2, att2, b2, srcA, eid, row_start, h2);

  dim3 g3(128 / 64, (N_NODES + 127) / 128);
  gemm_f32_tb<<<g3, 256, 0, stream>>>(h2, W_ih, gates, N_NODES, 128, 128);
  k_lstm<<<N_NODES, 128, 0, stream>>>(gates, b_ih, b_hh, fcW, fcb, out);
}

// Round 3
// 2212.115 us; speedup vs baseline: 1.5943x; 1.5943x over previous
//
#include <hip/hip_runtime.h>

#define N_NODES 50000
#define N_EDGES 500000
#define F_INDIM 388
#define H_HEADS 8
#define DD1 64
#define DD2 128
#define EDIM 16
#define HIDN 32

#define M_PAD 50048   // 391*128
#define K1_PAD 416    // 388 padded to mult of 32

typedef unsigned short u16;
typedef unsigned int u32;
typedef __attribute__((ext_vector_type(8))) short bf16x8;
typedef __attribute__((ext_vector_type(4))) float f32x4;

static __device__ __forceinline__ float bfu2f(u32 lo16) {
  union { u32 u; float f; } c;
  c.u = lo16 << 16;
  return c.f;
}
static __device__ __forceinline__ u16 f2bf(float f) {
  union { float f; u32 u; } c;
  c.f = f;
  u32 u = c.u + 0x7fffu + ((c.u >> 16) & 1u);
  return (u16)(u >> 16);
}

static __device__ __forceinline__ float waveSum(float v) {
#pragma unroll
  for (int off = 32; off > 0; off >>= 1) v += __shfl_xor(v, off, 64);
  return v;
}
static __device__ __forceinline__ void waveSum4(float& a, float& b, float& c, float& d) {
#pragma unroll
  for (int off = 32; off > 0; off >>= 1) {
    a += __shfl_xor(a, off, 64);
    b += __shfl_xor(b, off, 64);
    c += __shfl_xor(c, off, 64);
    d += __shfl_xor(d, off, 64);
  }
}

static __device__ __forceinline__ void gl_lds16(const void* g, void* l) {
  __builtin_amdgcn_global_load_lds((const __attribute__((address_space(1))) u32*)g,
                                   (__attribute__((address_space(3))) u32*)l, 16, 0, 0);
}

__global__ void k_zero(float* __restrict__ out, int n) {
  int i = blockIdx.x * blockDim.x + threadIdx.x;
  if (i < n) out[i] = 0.f;
}

// ---------------- CSR build ----------------
__global__ void k_hist(const int* __restrict__ dst, int* __restrict__ deg) {
  int e = blockIdx.x * blockDim.x + threadIdx.x;
  if (e < N_EDGES) atomicAdd(&deg[dst[e]], 1);
}

__global__ __launch_bounds__(1024) void k_scan(const int* __restrict__ deg,
                                               int* __restrict__ row_start) {
  __shared__ int wsum[16];
  __shared__ int carry_s;
  int tid = threadIdx.x;
  int lane = tid & 63, wv = tid >> 6;
  if (tid == 0) carry_s = 0;
  __syncthreads();
  for (int base = 0; base < N_NODES; base += 1024) {
    int i = base + tid;
    int v = (i < N_NODES) ? deg[i] : 0;
    int inc = v;
#pragma unroll
    for (int off = 1; off < 64; off <<= 1) {
      int t = __shfl_up(inc, off, 64);
      if (lane >= off) inc += t;
    }
    if (lane == 63) wsum[wv] = inc;
    __syncthreads();
    if (wv == 0 && lane < 16) {
      int s = wsum[lane];
#pragma unroll
      for (int off = 1; off < 16; off <<= 1) {
        int t = __shfl_up(s, off, 64);
        if (lane >= off) s += t;
      }
      wsum[lane] = s;
    }
    __syncthreads();
    int add = (wv > 0) ? wsum[wv - 1] : 0;
    int ex = carry_s + add + inc - v;
    if (i < N_NODES) row_start[i] = ex;
    __syncthreads();
    if (tid == 0) carry_s += wsum[15];
    __syncthreads();
  }
  if (threadIdx.x == 0) row_start[N_NODES] = carry_s;
}

__global__ void k_scatter(const int* __restrict__ dst, const int* __restrict__ row_start,
                          int* __restrict__ cursor, int* __restrict__ eid) {
  int e = blockIdx.x * blockDim.x + threadIdx.x;
  if (e < N_EDGES) {
    int d = dst[e];
    int pos = row_start[d] + atomicAdd(&cursor[d], 1);
    eid[pos] = e;
  }
}

// ---------------- conversions ----------------
__global__ void k_cvt_x(const float* __restrict__ x, u16* __restrict__ xb) {
  long t = (long)blockIdx.x * 256 + threadIdx.x;
  if (t >= (long)M_PAD * K1_PAD) return;
  int row = (int)(t / K1_PAD);
  int col = (int)(t % K1_PAD);
  float v = (row < N_NODES && col < F_INDIM) ? x[(size_t)row * F_INDIM + col] : 0.f;
  xb[t] = f2bf(v);
}

// W fp32 [K][N] -> WT bf16 [N][Kp], zero pad k>=K
__global__ void k_cvt_wT(const float* __restrict__ W, u16* __restrict__ WT, int K, int N, int Kp) {
  int t = blockIdx.x * 256 + threadIdx.x;
  if (t >= N * Kp) return;
  int n = t / Kp, k = t % Kp;
  WT[t] = f2bf(k < K ? W[(size_t)k * N + n] : 0.f);
}

__global__ void k_cvt(const float* __restrict__ W, u16* __restrict__ O, int n) {
  int t = blockIdx.x * 256 + threadIdx.x;
  if (t < n) O[t] = f2bf(W[t]);
}

// ---------------- MFMA bf16 GEMM: C[M,Nd] = A[M,K] @ BT[Nd,K]^T ----------------
// A bf16 row-major stride lda (rows padded to >= grid*128), BT bf16 [Nd][ldb].
// CF32: C fp32 else bf16. C rows guarded < M.
template <bool CF32>
__global__ __launch_bounds__(256) void gemm_mfma(const u16* __restrict__ A,
                                                 const u16* __restrict__ BT,
                                                 void* __restrict__ Cv, int M, int Nd, int K,
                                                 int lda, int ldb) {
  __shared__ u16 As[128 * 32];
  __shared__ u16 Bs[128 * 32];
  int tid = threadIdx.x;
  int lane = tid & 63;
  int wv = tid >> 6;
  int m_base = blockIdx.y * 128;
  int n_base = blockIdx.x * 128;
  int wrow = (wv >> 1) * 64;
  int wcol = (wv & 1) * 64;
  f32x4 acc[4][4];
#pragma unroll
  for (int i = 0; i < 4; ++i)
#pragma unroll
    for (int j = 0; j < 4; ++j)
#pragma unroll
      for (int r = 0; r < 4; ++r) acc[i][j][r] = 0.f;

  for (int k0 = 0; k0 < K; k0 += 32) {
    __syncthreads();
#pragma unroll
    for (int it = 0; it < 2; ++it) {
      int t = it * 256 + tid;
      int row = t >> 2;
      int kc = (t & 3) * 8;
      // wave-uniform LDS base (elements): (it*256 + wv*64) * 8 u16
      gl_lds16(A + (size_t)(m_base + row) * lda + k0 + kc, As + (size_t)(it * 256 + wv * 64) * 8);
      gl_lds16(BT + (size_t)(n_base + row) * ldb + k0 + kc, Bs + (size_t)(it * 256 + wv * 64) * 8);
    }
    __syncthreads();
    bf16x8 af[4], bfr[4];
#pragma unroll
    for (int i = 0; i < 4; ++i) {
      int r = wrow + i * 16 + (lane & 15);
      af[i] = *(const bf16x8*)(As + r * 32 + (lane >> 4) * 8);
    }
#pragma unroll
    for (int j = 0; j < 4; ++j) {
      int r = wcol + j * 16 + (lane & 15);
      bfr[j] = *(const bf16x8*)(Bs + r * 32 + (lane >> 4) * 8);
    }
#pragma unroll
    for (int i = 0; i < 4; ++i)
#pragma unroll
      for (int j = 0; j < 4; ++j)
        acc[i][j] = __builtin_amdgcn_mfma_f32_16x16x32_bf16(af[i], bfr[j], acc[i][j], 0, 0, 0);
  }
#pragma unroll
  for (int i = 0; i < 4; ++i) {
    int grow_base = m_base + wrow + i * 16 + (lane >> 4) * 4;
#pragma unroll
    for (int j = 0; j < 4; ++j) {
      int gcol = n_base + wcol + j * 16 + (lane & 15);
#pragma unroll
      for (int r = 0; r < 4; ++r) {
        int grow = grow_base + r;
        if (grow < M) {
          float v = acc[i][j][r];
          if (CF32)
            ((float*)Cv)[(size_t)grow * Nd + gcol] = v;
          else
            ((u16*)Cv)[(size_t)grow * Nd + gcol] = f2bf(v);
        }
      }
    }
  }
}

// ---------------- GAT layer 1 (D=64, concat) — bf16 in/out, 4x edge ILP ----------------
__global__ __launch_bounds__(512) void k_gat1(
    const u16* __restrict__ xl, const u16* __restrict__ xr, const float* __restrict__ ea,
    const float* __restrict__ We, const float* __restrict__ att, const float* __restrict__ bias,
    const int* __restrict__ src, const int* __restrict__ eid, const int* __restrict__ row_start,
    u16* __restrict__ out) {
  const int NC = H_HEADS * DD1;  // 512
  int n = blockIdx.x;
  int lane = threadIdx.x & 63;
  int h = threadIdx.x >> 6;
  __shared__ float la[EDIM];
  int r0 = row_start[n], r1 = row_start[n + 1];
  if (threadIdx.x < EDIM) {
    float s = 0.f;
    for (int i = r0; i < r1; ++i) s += ea[(size_t)eid[i] * EDIM + threadIdx.x];
    la[threadIdx.x] = s / (float)max(r1 - r0, 1);
  }
  __syncthreads();
  int col = h * DD1 + lane;
  float Wc[EDIM];
#pragma unroll
  for (int k = 0; k < EDIM; ++k) Wc[k] = We[k * NC + col];
  float attd = att[col];
  float xrd = bfu2f(xr[(size_t)n * NC + col]);
  float xlself = bfu2f(xl[(size_t)n * NC + col]);

  auto escore = [&](int e, float xv) -> float {
    const float4* ea4 = (const float4*)(ea + (size_t)e * EDIM);
    float4 v0 = ea4[0], v1 = ea4[1], v2 = ea4[2], v3 = ea4[3];
    float eacc = v0.x * Wc[0];
    eacc = fmaf(v0.y, Wc[1], eacc);
    eacc = fmaf(v0.z, Wc[2], eacc);
    eacc = fmaf(v0.w, Wc[3], eacc);
    eacc = fmaf(v1.x, Wc[4], eacc);
    eacc = fmaf(v1.y, Wc[5], eacc);
    eacc = fmaf(v1.z, Wc[6], eacc);
    eacc = fmaf(v1.w, Wc[7], eacc);
    eacc = fmaf(v2.x, Wc[8], eacc);
    eacc = fmaf(v2.y, Wc[9], eacc);
    eacc = fmaf(v2.z, Wc[10], eacc);
    eacc = fmaf(v2.w, Wc[11], eacc);
    eacc = fmaf(v3.x, Wc[12], eacc);
    eacc = fmaf(v3.y, Wc[13], eacc);
    eacc = fmaf(v3.z, Wc[14], eacc);
    eacc = fmaf(v3.w, Wc[15], eacc);
    float zz = xv + xrd + eacc;
    float mm = zz > 0.f ? zz : 0.2f * zz;
    return mm * attd;
  };

  // self loop
  float ee = 0.f;
#pragma unroll
  for (int k = 0; k < EDIM; ++k) ee = fmaf(la[k], Wc[k], ee);
  float z = xlself + xrd + ee;
  float m = z > 0.f ? z : 0.2f * z;
  float sc = waveSum(m * attd);
  float w = __expf(sc);
  float acc = w * xlself;
  float denom = w;

  int i = r0;
  for (; i + 4 <= r1; i += 4) {
    int e0 = eid[i], e1 = eid[i + 1], e2 = eid[i + 2], e3 = eid[i + 3];
    int s0 = src[e0], s1 = src[e1], s2 = src[e2], s3 = src[e3];
    float x0 = bfu2f(xl[(size_t)s0 * NC + col]);
    float x1 = bfu2f(xl[(size_t)s1 * NC + col]);
    float x2 = bfu2f(xl[(size_t)s2 * NC + col]);
    float x3 = bfu2f(xl[(size_t)s3 * NC + col]);
    float p0 = escore(e0, x0);
    float p1 = escore(e1, x1);
    float p2 = escore(e2, x2);
    float p3 = escore(e3, x3);
    waveSum4(p0, p1, p2, p3);
    float w0 = __expf(p0), w1 = __expf(p1), w2 = __expf(p2), w3 = __expf(p3);
    acc = fmaf(w0, x0, acc);
    acc = fmaf(w1, x1, acc);
    acc = fmaf(w2, x2, acc);
    acc = fmaf(w3, x3, acc);
    denom += (w0 + w1) + (w2 + w3);
  }
  for (; i < r1; ++i) {
    int e = eid[i];
    int s = src[e];
    float xv = bfu2f(xl[(size_t)s * NC + col]);
    float p = waveSum(escore(e, xv));
    float ww = __expf(p);
    acc = fmaf(ww, xv, acc);
    denom += ww;
  }
  out[(size_t)n * NC + col] = f2bf(tanhf(acc / denom + bias[col]));
}

// ---------------- GAT layer 2 (D=128, mean heads) — bf16 in/out, 4x edge ILP ----------------
__global__ __launch_bounds__(512) void k_gat2(
    const u16* __restrict__ xl, const u16* __restrict__ xr, const float* __restrict__ ea,
    const float* __restrict__ We, const float* __restrict__ att, const float* __restrict__ bias,
    const int* __restrict__ src, const int* __restrict__ eid, const int* __restrict__ row_start,
    u16* __restrict__ out) {
  const int NC = H_HEADS * DD2;  // 1024
  int n = blockIdx.x;
  int lane = threadIdx.x & 63;
  int h = threadIdx.x >> 6;
  __shared__ float la[EDIM];
  __shared__ float hsum[H_HEADS][DD2];
  int r0 = row_start[n], r1 = row_start[n + 1];
  if (threadIdx.x < EDIM) {
    float s = 0.f;
    for (int i = r0; i < r1; ++i) s += ea[(size_t)eid[i] * EDIM + threadIdx.x];
    la[threadIdx.x] = s / (float)max(r1 - r0, 1);
  }
  __syncthreads();
  int col = h * DD2 + lane * 2;
  float Wcx[EDIM], Wcy[EDIM];
#pragma unroll
  for (int k = 0; k < EDIM; ++k) {
    float2 t = *(const float2*)(We + k * NC + col);
    Wcx[k] = t.x;
    Wcy[k] = t.y;
  }
  float2 attd = *(const float2*)(att + col);
  u32 xru = *(const u32*)(xr + (size_t)n * NC + col);
  u32 xlu = *(const u32*)(xl + (size_t)n * NC + col);
  float xrdx = bfu2f(xru & 0xffff), xrdy = bfu2f(xru >> 16);
  float xlsx = bfu2f(xlu & 0xffff), xlsy = bfu2f(xlu >> 16);

  auto escore2 = [&](int e, float xvx, float xvy) -> float {
    const float4* ea4 = (const float4*)(ea + (size_t)e * EDIM);
    float4 v0 = ea4[0], v1 = ea4[1], v2 = ea4[2], v3 = ea4[3];
    float ex = v0.x * Wcx[0], ey = v0.x * Wcy[0];
    ex = fmaf(v0.y, Wcx[1], ex); ey = fmaf(v0.y, Wcy[1], ey);
    ex = fmaf(v0.z, Wcx[2], ex); ey = fmaf(v0.z, Wcy[2], ey);
    ex = fmaf(v0.w, Wcx[3], ex); ey = fmaf(v0.w, Wcy[3], ey);
    ex = fmaf(v1.x, Wcx[4], ex); ey = fmaf(v1.x, Wcy[4], ey);
    ex = fmaf(v1.y, Wcx[5], ex); ey = fmaf(v1.y, Wcy[5], ey);
    ex = fmaf(v1.z, Wcx[6], ex); ey = fmaf(v1.z, Wcy[6], ey);
    ex = fmaf(v1.w, Wcx[7], ex); ey = fmaf(v1.w, Wcy[7], ey);
    ex = fmaf(v2.x, Wcx[8], ex); ey = fmaf(v2.x, Wcy[8], ey);
    ex = fmaf(v2.y, Wcx[9], ex); ey = fmaf(v2.y, Wcy[9], ey);
    ex = fmaf(v2.z, Wcx[10], ex); ey = fmaf(v2.z, Wcy[10], ey);
    ex = fmaf(v2.w, Wcx[11], ex); ey = fmaf(v2.w, Wcy[11], ey);
    ex = fmaf(v3.x, Wcx[12], ex); ey = fmaf(v3.x, Wcy[12], ey);
    ex = fmaf(v3.y, Wcx[13], ex); ey = fmaf(v3.y, Wcy[13], ey);
    ex = fmaf(v3.z, Wcx[14], ex); ey = fmaf(v3.z, Wcy[14], ey);
    ex = fmaf(v3.w, Wcx[15], ex); ey = fmaf(v3.w, Wcy[15], ey);
    float zx = xvx + xrdx + ex, zy = xvy + xrdy + ey;
    float mx = zx > 0.f ? zx : 0.2f * zx, my = zy > 0.f ? zy : 0.2f * zy;
    return mx * attd.x + my * attd.y;
  };

  // self loop
  float eex = 0.f, eey = 0.f;
#pragma unroll
  for (int k = 0; k < EDIM; ++k) {
    eex = fmaf(la[k], Wcx[k], eex);
    eey = fmaf(la[k], Wcy[k], eey);
  }
  float zx = xlsx + xrdx + eex, zy = xlsy + xrdy + eey;
  float mx = zx > 0.f ? zx : 0.2f * zx, my = zy > 0.f ? zy : 0.2f * zy;
  float sc = waveSum(mx * attd.x + my * attd.y);
  float w = __expf(sc);
  float accx = w * xlsx, accy = w * xlsy, denom = w;

  int i = r0;
  for (; i + 4 <= r1; i += 4) {
    int e0 = eid[i], e1 = eid[i + 1], e2 = eid[i + 2], e3 = eid[i + 3];
    int s0 = src[e0], s1 = src[e1], s2 = src[e2], s3 = src[e3];
    u32 u0 = *(const u32*)(xl + (size_t)s0 * NC + col);
    u32 u1 = *(const u32*)(xl + (size_t)s1 * NC + col);
    u32 u2 = *(const u32*)(xl + (size_t)s2 * NC + col);
    u32 u3 = *(const u32*)(xl + (size_t)s3 * NC + col);
    float x0x = bfu2f(u0 & 0xffff), x0y = bfu2f(u0 >> 16);
    float x1x = bfu2f(u1 & 0xffff), x1y = bfu2f(u1 >> 16);
    float x2x = bfu2f(u2 & 0xffff), x2y = bfu2f(u2 >> 16);
    float x3x = bfu2f(u3 & 0xffff), x3y = bfu2f(u3 >> 16);
    float p0 = escore2(e0, x0x, x0y);
    float p1 = escore2(e1, x1x, x1y);
    float p2 = escore2(e2, x2x, x2y);
    float p3 = escore2(e3, x3x, x3y);
    waveSum4(p0, p1, p2, p3);
    float w0 = __expf(p0), w1 = __expf(p1), w2 = __expf(p2), w3 = __expf(p3);
    accx = fmaf(w0, x0x, accx); accy = fmaf(w0, x0y, accy);
    accx = fmaf(w1, x1x, accx); accy = fmaf(w1, x1y, accy);
    accx = fmaf(w2, x2x, accx); accy = fmaf(w2, x2y, accy);
    accx = fmaf(w3, x3x, accx); accy = fmaf(w3, x3y, accy);
    denom += (w0 + w1) + (w2 + w3);
  }
  for (; i < r1; ++i) {
    int e = eid[i];
    int s = src[e];
    u32 u0 = *(const u32*)(xl + (size_t)s * NC + col);
    float xvx = bfu2f(u0 & 0xffff), xvy = bfu2f(u0 >> 16);
    float p = waveSum(escore2(e, xvx, xvy));
    float ww = __expf(p);
    accx = fmaf(ww, xvx, accx);
    accy = fmaf(ww, xvy, accy);
    denom += ww;
  }
  float inv = 1.f / denom;
  hsum[h][lane * 2] = accx * inv;
  hsum[h][lane * 2 + 1] = accy * inv;
  __syncthreads();
  if (threadIdx.x < DD2) {
    float s = 0.f;
#pragma unroll
    for (int hh = 0; hh < H_HEADS; ++hh) s += hsum[hh][threadIdx.x];
    out[(size_t)n * DD2 + threadIdx.x] = f2bf(tanhf(s * 0.125f + bias[threadIdx.x]));
  }
}

// ---------------- LSTM (single step, h0=c0=0) + FC ----------------
__global__ __launch_bounds__(128) void k_lstm(const float* __restrict__ gates,
                                              const float* __restrict__ b_ih,
                                              const float* __restrict__ b_hh,
                                              const float* __restrict__ fcW,
                                              const float* __restrict__ fcb,
                                              float* __restrict__ out) {
  int n = blockIdx.x;
  int j = threadIdx.x;
  __shared__ float gs[128];
  gs[j] = gates[(size_t)n * 128 + j] + b_ih[j] + b_hh[j];
  __syncthreads();
  if (j < 32) {
    float iv = gs[j], gv = gs[64 + j], ov = gs[96 + j];
    float c = (1.f / (1.f + __expf(-iv))) * tanhf(gv);
    float hd = (1.f / (1.f + __expf(-ov))) * tanhf(c);
    float p = hd * fcW[j];
#pragma unroll
    for (int off = 16; off > 0; off >>= 1) p += __shfl_down(p, off, 32);
    if (j == 0) out[n] = p + fcb[0];
  }
}

extern "C" void kernel_launch(void* const* d_in, const int* in_sizes, int n_in, void* d_out,
                              int out_size, void* d_ws, size_t ws_size, hipStream_t stream) {
  const float* x = (const float*)d_in[0];
  const int* ei = (const int*)d_in[1];
  const float* ea = (const float*)d_in[2];
  const float* Wl1 = (const float*)d_in[3];
  const float* Wr1 = (const float*)d_in[4];
  const float* We1 = (const float*)d_in[5];
  const float* att1 = (const float*)d_in[6];
  const float* b1 = (const float*)d_in[7];
  const float* Wl2 = (const float*)d_in[8];
  const float* Wr2 = (const float*)d_in[9];
  const float* We2 = (const float*)d_in[10];
  const float* att2 = (const float*)d_in[11];
  const float* b2 = (const float*)d_in[12];
  const float* W_ih = (const float*)d_in[13];
  const float* b_ih = (const float*)d_in[15];
  const float* b_hh = (const float*)d_in[16];
  const float* fcW = (const float*)d_in[17];
  const float* fcb = (const float*)d_in[18];
  float* out = (float*)d_out;
  const int* srcA = ei;
  const int* dstA = ei + N_EDGES;

  char* ws = (char*)d_ws;
  // region plan (bytes):
  const size_t SZ_XL1 = (size_t)N_NODES * 512 * 2;    // 51,200,000
  const size_t SZ_P0 = (size_t)N_NODES * 1024 * 2;    // 102,400,000 (xl1+xr1 | xl2)
  const size_t SZ_P1 = SZ_P0;                         // xbf | xr2
  const size_t SZ_H1 = (size_t)M_PAD * 512 * 2;       // 51,249,152
  const size_t SZ_H2 = (size_t)M_PAD * 128 * 2;       // 12,812,288
  size_t P0 = 0;
  size_t P1 = P0 + SZ_P0;
  size_t P2 = P1 + SZ_P1;
  size_t P3 = P2 + SZ_H1;
  size_t off = P3;
  auto take = [&](size_t bytes) -> char* {
    off = (off + 255) & ~(size_t)255;
    char* p = ws + off;
    off += bytes;
    return p;
  };
  u16* W1lT = (u16*)take((size_t)512 * K1_PAD * 2);
  u16* W1rT = (u16*)take((size_t)512 * K1_PAD * 2);
  u16* W2lT = (u16*)take((size_t)1024 * 512 * 2);
  u16* W2rT = (u16*)take((size_t)1024 * 512 * 2);
  u16* WihB = (u16*)take((size_t)128 * 128 * 2);
  int* deg = (int*)take((size_t)N_NODES * 4);
  int* cursor = (int*)take((size_t)N_NODES * 4);
  int* row_start = (int*)take((size_t)(N_NODES + 1) * 4);
  int* eid = (int*)take((size_t)N_EDGES * 4);

  if (off > ws_size) {
    k_zero<<<(out_size + 255) / 256, 256, 0, stream>>>(out, out_size);
    return;
  }

  u16* xl1 = (u16*)(ws + P0);
  u16* xr1 = (u16*)(ws + P0 + SZ_XL1);
  u16* xl2 = (u16*)(ws + P0);
  u16* xbf = (u16*)(ws + P1);
  u16* xr2 = (u16*)(ws + P1);
  u16* h1 = (u16*)(ws + P2);
  u16* h2 = (u16*)(ws + P2);
  float* gates = (float*)(ws + P2 + SZ_H2);

  hipMemsetAsync(deg, 0, (size_t)N_NODES * 4, stream);
  hipMemsetAsync(cursor, 0, (size_t)N_NODES * 4, stream);
  k_hist<<<(N_EDGES + 255) / 256, 256, 0, stream>>>(dstA, deg);
  k_scan<<<1, 1024, 0, stream>>>(deg, row_start);
  k_scatter<<<(N_EDGES + 255) / 256, 256, 0, stream>>>(dstA, row_start, cursor, eid);

  // conversions
  {
    long tot = (long)M_PAD * K1_PAD;
    k_cvt_x<<<(unsigned)((tot + 255) / 256), 256, 0, stream>>>(x, xbf);
    k_cvt_wT<<<(512 * K1_PAD + 255) / 256, 256, 0, stream>>>(Wl1, W1lT, F_INDIM, 512, K1_PAD);
    k_cvt_wT<<<(512 * K1_PAD + 255) / 256, 256, 0, stream>>>(Wr1, W1rT, F_INDIM, 512, K1_PAD);
    k_cvt_wT<<<(1024 * 512 + 255) / 256, 256, 0, stream>>>(Wl2, W2lT, 512, 1024, 512);
    k_cvt_wT<<<(1024 * 512 + 255) / 256, 256, 0, stream>>>(Wr2, W2rT, 512, 1024, 512);
    k_cvt<<<(128 * 128 + 255) / 256, 256, 0, stream>>>(W_ih, WihB, 128 * 128);
  }

  const int MB = M_PAD / 128;  // 391
  // layer 1 GEMMs: [50000 x 416] @ [416 x 512]
  {
    dim3 g(512 / 128, MB);
    gemm_mfma<false><<<g, 256, 0, stream>>>(xbf, W1lT, xl1, N_NODES, 512, K1_PAD, K1_PAD, K1_PAD);
    gemm_mfma<false><<<g, 256, 0, stream>>>(xbf, W1rT, xr1, N_NODES, 512, K1_PAD, K1_PAD, K1_PAD);
  }
  k_gat1<<<N_NODES, 512, 0, stream>>>(xl1, xr1, ea, We1, att1, b1, srcA, eid, row_start, h1);

  // layer 2 GEMMs: [50000 x 512] @ [512 x 1024]
  {
    dim3 g(1024 / 128, MB);
    gemm_mfma<false><<<g, 256, 0, stream>>>(h1, W2lT, xl2, N_NODES, 1024, 512, 512, 512);
    gemm_mfma<false><<<g, 256, 0, stream>>>(h1, W2rT, xr2, N_NODES, 1024, 512, 512, 512);
  }
  k_gat2<<<N_NODES, 512, 0, stream>>>(xl2, xr2, ea, We2, att2, b2, srcA, eid, row_start, h2);

  // LSTM gates GEMM: [50000 x 128] @ [128 x 128] (BT = W_ih as-is)
  {
    dim3 g(1, MB);
    gemm_mfma<true><<<g, 256, 0, stream>>>(h2, WihB, gates, N_NODES, 128, 128, 128, 128);
  }
  k_lstm<<<N_NODES, 128, 0, stream>>>(gates, b_ih, b_hh, fcW, fcb, out);
}

// Round 4
// 1576.308 us; speedup vs baseline: 2.2373x; 1.4034x over previous
//
#include <hip/hip_runtime.h>

#define N_NODES 50000
#define N_EDGES 500000
#define F_INDIM 388
#define H_HEADS 8
#define DD1 64
#define DD2 128
#define EDIM 16
#define HIDN 32

#define M_PAD 50048   // 391*128
#define K1_PAD 416    // 388 padded to mult of 32

typedef unsigned short u16;
typedef unsigned int u32;
typedef __attribute__((ext_vector_type(8))) short bf16x8;
typedef __attribute__((ext_vector_type(4))) float f32x4;

static __device__ __forceinline__ float bfu2f(u32 lo16) {
  union { u32 u; float f; } c;
  c.u = lo16 << 16;
  return c.f;
}
static __device__ __forceinline__ u16 f2bf(float f) {
  union { float f; u32 u; } c;
  c.f = f;
  u32 u = c.u + 0x7fffu + ((c.u >> 16) & 1u);
  return (u16)(u >> 16);
}

static __device__ __forceinline__ float waveSum(float v) {
#pragma unroll
  for (int off = 32; off > 0; off >>= 1) v += __shfl_xor(v, off, 64);
  return v;
}
static __device__ __forceinline__ void waveSum4(float& a, float& b, float& c, float& d) {
#pragma unroll
  for (int off = 32; off > 0; off >>= 1) {
    a += __shfl_xor(a, off, 64);
    b += __shfl_xor(b, off, 64);
    c += __shfl_xor(c, off, 64);
    d += __shfl_xor(d, off, 64);
  }
}

static __device__ __forceinline__ void gl_lds16(const void* g, void* l) {
  __builtin_amdgcn_global_load_lds((const __attribute__((address_space(1))) u32*)g,
                                   (__attribute__((address_space(3))) u32*)l, 16, 0, 0);
}

__global__ void k_zero(float* __restrict__ out, int n) {
  int i = blockIdx.x * blockDim.x + threadIdx.x;
  if (i < n) out[i] = 0.f;
}

// ---------------- CSR build ----------------
__global__ void k_hist(const int* __restrict__ dst, int* __restrict__ deg) {
  int e = blockIdx.x * blockDim.x + threadIdx.x;
  if (e < N_EDGES) atomicAdd(&deg[dst[e]], 1);
}

__global__ __launch_bounds__(1024) void k_scan(const int* __restrict__ deg,
                                               int* __restrict__ row_start) {
  __shared__ int wsum[16];
  __shared__ int carry_s;
  int tid = threadIdx.x;
  int lane = tid & 63, wv = tid >> 6;
  if (tid == 0) carry_s = 0;
  __syncthreads();
  for (int base = 0; base < N_NODES; base += 1024) {
    int i = base + tid;
    int v = (i < N_NODES) ? deg[i] : 0;
    int inc = v;
#pragma unroll
    for (int off = 1; off < 64; off <<= 1) {
      int t = __shfl_up(inc, off, 64);
      if (lane >= off) inc += t;
    }
    if (lane == 63) wsum[wv] = inc;
    __syncthreads();
    if (wv == 0 && lane < 16) {
      int s = wsum[lane];
#pragma unroll
      for (int off = 1; off < 16; off <<= 1) {
        int t = __shfl_up(s, off, 64);
        if (lane >= off) s += t;
      }
      wsum[lane] = s;
    }
    __syncthreads();
    int add = (wv > 0) ? wsum[wv - 1] : 0;
    int ex = carry_s + add + inc - v;
    if (i < N_NODES) row_start[i] = ex;
    __syncthreads();
    if (tid == 0) carry_s += wsum[15];
    __syncthreads();
  }
  if (threadIdx.x == 0) row_start[N_NODES] = carry_s;
}

__global__ void k_scatter(const int* __restrict__ dst, const int* __restrict__ src,
                          const int* __restrict__ row_start, int* __restrict__ cursor,
                          int* __restrict__ eid, int* __restrict__ srcp) {
  int e = blockIdx.x * blockDim.x + threadIdx.x;
  if (e < N_EDGES) {
    int d = dst[e];
    int pos = row_start[d] + atomicAdd(&cursor[d], 1);
    eid[pos] = e;
    srcp[pos] = src[e];
  }
}

// ---------------- conversions ----------------
__global__ void k_cvt_x(const float* __restrict__ x, u16* __restrict__ xb) {
  long t = (long)blockIdx.x * 256 + threadIdx.x;
  if (t >= (long)M_PAD * K1_PAD) return;
  int row = (int)(t / K1_PAD);
  int col = (int)(t % K1_PAD);
  float v = (row < N_NODES && col < F_INDIM) ? x[(size_t)row * F_INDIM + col] : 0.f;
  xb[t] = f2bf(v);
}

// W fp32 [K][N] -> WT bf16 [N][Kp], zero pad k>=K
__global__ void k_cvt_wT(const float* __restrict__ W, u16* __restrict__ WT, int K, int N, int Kp) {
  int t = blockIdx.x * 256 + threadIdx.x;
  if (t >= N * Kp) return;
  int n = t / Kp, k = t % Kp;
  WT[t] = f2bf(k < K ? W[(size_t)k * N + n] : 0.f);
}

__global__ void k_cvt(const float* __restrict__ W, u16* __restrict__ O, int n) {
  int t = blockIdx.x * 256 + threadIdx.x;
  if (t < n) O[t] = f2bf(W[t]);
}

// ---------------- MFMA bf16 GEMM: C[M,Nd] = A[M,K] @ BT[Nd,K]^T ----------------
template <bool CF32>
__global__ __launch_bounds__(256) void gemm_mfma(const u16* __restrict__ A,
                                                 const u16* __restrict__ BT,
                                                 void* __restrict__ Cv, int M, int Nd, int K,
                                                 int lda, int ldb) {
  __shared__ u16 As[128 * 32];
  __shared__ u16 Bs[128 * 32];
  int tid = threadIdx.x;
  int lane = tid & 63;
  int wv = tid >> 6;
  int m_base = blockIdx.y * 128;
  int n_base = blockIdx.x * 128;
  int wrow = (wv >> 1) * 64;
  int wcol = (wv & 1) * 64;
  f32x4 acc[4][4];
#pragma unroll
  for (int i = 0; i < 4; ++i)
#pragma unroll
    for (int j = 0; j < 4; ++j)
#pragma unroll
      for (int r = 0; r < 4; ++r) acc[i][j][r] = 0.f;

  for (int k0 = 0; k0 < K; k0 += 32) {
    __syncthreads();
#pragma unroll
    for (int it = 0; it < 2; ++it) {
      int t = it * 256 + tid;
      int row = t >> 2;
      int kc = (t & 3) * 8;
      gl_lds16(A + (size_t)(m_base + row) * lda + k0 + kc, As + (size_t)(it * 256 + wv * 64) * 8);
      gl_lds16(BT + (size_t)(n_base + row) * ldb + k0 + kc, Bs + (size_t)(it * 256 + wv * 64) * 8);
    }
    __syncthreads();
    bf16x8 af[4], bfr[4];
#pragma unroll
    for (int i = 0; i < 4; ++i) {
      int r = wrow + i * 16 + (lane & 15);
      af[i] = *(const bf16x8*)(As + r * 32 + (lane >> 4) * 8);
    }
#pragma unroll
    for (int j = 0; j < 4; ++j) {
      int r = wcol + j * 16 + (lane & 15);
      bfr[j] = *(const bf16x8*)(Bs + r * 32 + (lane >> 4) * 8);
    }
#pragma unroll
    for (int i = 0; i < 4; ++i)
#pragma unroll
      for (int j = 0; j < 4; ++j)
        acc[i][j] = __builtin_amdgcn_mfma_f32_16x16x32_bf16(af[i], bfr[j], acc[i][j], 0, 0, 0);
  }
#pragma unroll
  for (int i = 0; i < 4; ++i) {
    int grow_base = m_base + wrow + i * 16 + (lane >> 4) * 4;
#pragma unroll
    for (int j = 0; j < 4; ++j) {
      int gcol = n_base + wcol + j * 16 + (lane & 15);
#pragma unroll
      for (int r = 0; r < 4; ++r) {
        int grow = grow_base + r;
        if (grow < M) {
          float v = acc[i][j][r];
          if (CF32)
            ((float*)Cv)[(size_t)grow * Nd + gcol] = v;
          else
            ((u16*)Cv)[(size_t)grow * Nd + gcol] = f2bf(v);
        }
      }
    }
  }
}

// ---------------- GAT layer 1 (D=64, concat) ----------------
// parallel la + srcp direct indexing + self-loop last
__global__ __launch_bounds__(512) void k_gat1(
    const u16* __restrict__ xl, const u16* __restrict__ xr, const float* __restrict__ ea,
    const float* __restrict__ We, const float* __restrict__ att, const float* __restrict__ bias,
    const int* __restrict__ srcp, const int* __restrict__ eid, const int* __restrict__ row_start,
    u16* __restrict__ out) {
  const int NC = H_HEADS * DD1;  // 512
  int n = blockIdx.x;
  int tid = threadIdx.x;
  int lane = tid & 63;
  int h = tid >> 6;
  __shared__ float laP[512];
  __shared__ float la[EDIM];
  int r0 = row_start[n], r1 = row_start[n + 1];
  int deg = r1 - r0;

  // parallel la partials: thread = (edge-slot i0 = tid>>4, dim k = tid&15)
  {
    int k = tid & 15, i0 = tid >> 4;
    float s = 0.f;
    for (int i = i0; i < deg; i += 32) s += ea[(size_t)eid[r0 + i] * EDIM + k];
    laP[tid] = s;
  }

  int col = h * DD1 + lane;
  float Wc[EDIM];
#pragma unroll
  for (int k = 0; k < EDIM; ++k) Wc[k] = We[k * NC + col];
  float attd = att[col];
  float xrd = bfu2f(xr[(size_t)n * NC + col]);
  float xlself = bfu2f(xl[(size_t)n * NC + col]);

  auto escore = [&](int e, float xv) -> float {
    const float4* ea4 = (const float4*)(ea + (size_t)e * EDIM);
    float4 v0 = ea4[0], v1 = ea4[1], v2 = ea4[2], v3 = ea4[3];
    float eacc = v0.x * Wc[0];
    eacc = fmaf(v0.y, Wc[1], eacc);
    eacc = fmaf(v0.z, Wc[2], eacc);
    eacc = fmaf(v0.w, Wc[3], eacc);
    eacc = fmaf(v1.x, Wc[4], eacc);
    eacc = fmaf(v1.y, Wc[5], eacc);
    eacc = fmaf(v1.z, Wc[6], eacc);
    eacc = fmaf(v1.w, Wc[7], eacc);
    eacc = fmaf(v2.x, Wc[8], eacc);
    eacc = fmaf(v2.y, Wc[9], eacc);
    eacc = fmaf(v2.z, Wc[10], eacc);
    eacc = fmaf(v2.w, Wc[11], eacc);
    eacc = fmaf(v3.x, Wc[12], eacc);
    eacc = fmaf(v3.y, Wc[13], eacc);
    eacc = fmaf(v3.z, Wc[14], eacc);
    eacc = fmaf(v3.w, Wc[15], eacc);
    float zz = xv + xrd + eacc;
    float mm = zz > 0.f ? zz : 0.2f * zz;
    return mm * attd;
  };

  float acc = 0.f, denom = 0.f;
  int i = r0;
  for (; i + 4 <= r1; i += 4) {
    int e0 = eid[i], e1 = eid[i + 1], e2 = eid[i + 2], e3 = eid[i + 3];
    int s0 = srcp[i], s1 = srcp[i + 1], s2 = srcp[i + 2], s3 = srcp[i + 3];
    float x0 = bfu2f(xl[(size_t)s0 * NC + col]);
    float x1 = bfu2f(xl[(size_t)s1 * NC + col]);
    float x2 = bfu2f(xl[(size_t)s2 * NC + col]);
    float x3 = bfu2f(xl[(size_t)s3 * NC + col]);
    float p0 = escore(e0, x0);
    float p1 = escore(e1, x1);
    float p2 = escore(e2, x2);
    float p3 = escore(e3, x3);
    waveSum4(p0, p1, p2, p3);
    float w0 = __expf(p0), w1 = __expf(p1), w2 = __expf(p2), w3 = __expf(p3);
    acc = fmaf(w0, x0, acc);
    acc = fmaf(w1, x1, acc);
    acc = fmaf(w2, x2, acc);
    acc = fmaf(w3, x3, acc);
    denom += (w0 + w1) + (w2 + w3);
  }
  for (; i < r1; ++i) {
    int e = eid[i];
    int s = srcp[i];
    float xv = bfu2f(xl[(size_t)s * NC + col]);
    float p = waveSum(escore(e, xv));
    float ww = __expf(p);
    acc = fmaf(ww, xv, acc);
    denom += ww;
  }

  // reduce la, then self-loop
  __syncthreads();
  if (tid < EDIM) {
    float s = 0.f;
#pragma unroll
    for (int g = 0; g < 32; ++g) s += laP[g * 16 + tid];
    la[tid] = s / (float)max(deg, 1);
  }
  __syncthreads();
  float ee = 0.f;
#pragma unroll
  for (int k = 0; k < EDIM; ++k) ee = fmaf(la[k], Wc[k], ee);
  float z = xlself + xrd + ee;
  float m = z > 0.f ? z : 0.2f * z;
  float sc = waveSum(m * attd);
  float w = __expf(sc);
  acc = fmaf(w, xlself, acc);
  denom += w;

  out[(size_t)n * NC + col] = f2bf(tanhf(acc / denom + bias[col]));
}

// ---------------- GAT layer 2 (D=128, mean heads) ----------------
__global__ __launch_bounds__(512) void k_gat2(
    const u16* __restrict__ xl, const u16* __restrict__ xr, const float* __restrict__ ea,
    const float* __restrict__ We, const float* __restrict__ att, const float* __restrict__ bias,
    const int* __restrict__ srcp, const int* __restrict__ eid, const int* __restrict__ row_start,
    u16* __restrict__ out) {
  const int NC = H_HEADS * DD2;  // 1024
  int n = blockIdx.x;
  int tid = threadIdx.x;
  int lane = tid & 63;
  int h = tid >> 6;
  __shared__ float laP[512];
  __shared__ float la[EDIM];
  __shared__ float hsum[H_HEADS][DD2];
  int r0 = row_start[n], r1 = row_start[n + 1];
  int deg = r1 - r0;

  {
    int k = tid & 15, i0 = tid >> 4;
    float s = 0.f;
    for (int i = i0; i < deg; i += 32) s += ea[(size_t)eid[r0 + i] * EDIM + k];
    laP[tid] = s;
  }

  int col = h * DD2 + lane * 2;
  float Wcx[EDIM], Wcy[EDIM];
#pragma unroll
  for (int k = 0; k < EDIM; ++k) {
    float2 t = *(const float2*)(We + k * NC + col);
    Wcx[k] = t.x;
    Wcy[k] = t.y;
  }
  float2 attd = *(const float2*)(att + col);
  u32 xru = *(const u32*)(xr + (size_t)n * NC + col);
  u32 xlu = *(const u32*)(xl + (size_t)n * NC + col);
  float xrdx = bfu2f(xru & 0xffff), xrdy = bfu2f(xru >> 16);
  float xlsx = bfu2f(xlu & 0xffff), xlsy = bfu2f(xlu >> 16);

  auto escore2 = [&](int e, float xvx, float xvy) -> float {
    const float4* ea4 = (const float4*)(ea + (size_t)e * EDIM);
    float4 v0 = ea4[0], v1 = ea4[1], v2 = ea4[2], v3 = ea4[3];
    float ex = v0.x * Wcx[0], ey = v0.x * Wcy[0];
    ex = fmaf(v0.y, Wcx[1], ex); ey = fmaf(v0.y, Wcy[1], ey);
    ex = fmaf(v0.z, Wcx[2], ex); ey = fmaf(v0.z, Wcy[2], ey);
    ex = fmaf(v0.w, Wcx[3], ex); ey = fmaf(v0.w, Wcy[3], ey);
    ex = fmaf(v1.x, Wcx[4], ex); ey = fmaf(v1.x, Wcy[4], ey);
    ex = fmaf(v1.y, Wcx[5], ex); ey = fmaf(v1.y, Wcy[5], ey);
    ex = fmaf(v1.z, Wcx[6], ex); ey = fmaf(v1.z, Wcy[6], ey);
    ex = fmaf(v1.w, Wcx[7], ex); ey = fmaf(v1.w, Wcy[7], ey);
    ex = fmaf(v2.x, Wcx[8], ex); ey = fmaf(v2.x, Wcy[8], ey);
    ex = fmaf(v2.y, Wcx[9], ex); ey = fmaf(v2.y, Wcy[9], ey);
    ex = fmaf(v2.z, Wcx[10], ex); ey = fmaf(v2.z, Wcy[10], ey);
    ex = fmaf(v2.w, Wcx[11], ex); ey = fmaf(v2.w, Wcy[11], ey);
    ex = fmaf(v3.x, Wcx[12], ex); ey = fmaf(v3.x, Wcy[12], ey);
    ex = fmaf(v3.y, Wcx[13], ex); ey = fmaf(v3.y, Wcy[13], ey);
    ex = fmaf(v3.z, Wcx[14], ex); ey = fmaf(v3.z, Wcy[14], ey);
    ex = fmaf(v3.w, Wcx[15], ex); ey = fmaf(v3.w, Wcy[15], ey);
    float zx = xvx + xrdx + ex, zy = xvy + xrdy + ey;
    float mx = zx > 0.f ? zx : 0.2f * zx, my = zy > 0.f ? zy : 0.2f * zy;
    return mx * attd.x + my * attd.y;
  };

  float accx = 0.f, accy = 0.f, denom = 0.f;
  int i = r0;
  for (; i + 4 <= r1; i += 4) {
    int e0 = eid[i], e1 = eid[i + 1], e2 = eid[i + 2], e3 = eid[i + 3];
    int s0 = srcp[i], s1 = srcp[i + 1], s2 = srcp[i + 2], s3 = srcp[i + 3];
    u32 u0 = *(const u32*)(xl + (size_t)s0 * NC + col);
    u32 u1 = *(const u32*)(xl + (size_t)s1 * NC + col);
    u32 u2 = *(const u32*)(xl + (size_t)s2 * NC + col);
    u32 u3 = *(const u32*)(xl + (size_t)s3 * NC + col);
    float x0x = bfu2f(u0 & 0xffff), x0y = bfu2f(u0 >> 16);
    float x1x = bfu2f(u1 & 0xffff), x1y = bfu2f(u1 >> 16);
    float x2x = bfu2f(u2 & 0xffff), x2y = bfu2f(u2 >> 16);
    float x3x = bfu2f(u3 & 0xffff), x3y = bfu2f(u3 >> 16);
    float p0 = escore2(e0, x0x, x0y);
    float p1 = escore2(e1, x1x, x1y);
    float p2 = escore2(e2, x2x, x2y);
    float p3 = escore2(e3, x3x, x3y);
    waveSum4(p0, p1, p2, p3);
    float w0 = __expf(p0), w1 = __expf(p1), w2 = __expf(p2), w3 = __expf(p3);
    accx = fmaf(w0, x0x, accx); accy = fmaf(w0, x0y, accy);
    accx = fmaf(w1, x1x, accx); accy = fmaf(w1, x1y, accy);
    accx = fmaf(w2, x2x, accx); accy = fmaf(w2, x2y, accy);
    accx = fmaf(w3, x3x, accx); accy = fmaf(w3, x3y, accy);
    denom += (w0 + w1) + (w2 + w3);
  }
  for (; i < r1; ++i) {
    int e = eid[i];
    int s = srcp[i];
    u32 u0 = *(const u32*)(xl + (size_t)s * NC + col);
    float xvx = bfu2f(u0 & 0xffff), xvy = bfu2f(u0 >> 16);
    float p = waveSum(escore2(e, xvx, xvy));
    float ww = __expf(p);
    accx = fmaf(ww, xvx, accx);
    accy = fmaf(ww, xvy, accy);
    denom += ww;
  }

  __syncthreads();
  if (tid < EDIM) {
    float s = 0.f;
#pragma unroll
    for (int g = 0; g < 32; ++g) s += laP[g * 16 + tid];
    la[tid] = s / (float)max(deg, 1);
  }
  __syncthreads();
  float eex = 0.f, eey = 0.f;
#pragma unroll
  for (int k = 0; k < EDIM; ++k) {
    eex = fmaf(la[k], Wcx[k], eex);
    eey = fmaf(la[k], Wcy[k], eey);
  }
  float zx = xlsx + xrdx + eex, zy = xlsy + xrdy + eey;
  float mx = zx > 0.f ? zx : 0.2f * zx, my = zy > 0.f ? zy : 0.2f * zy;
  float sc = waveSum(mx * attd.x + my * attd.y);
  float w = __expf(sc);
  accx = fmaf(w, xlsx, accx);
  accy = fmaf(w, xlsy, accy);
  denom += w;

  float inv = 1.f / denom;
  hsum[h][lane * 2] = accx * inv;
  hsum[h][lane * 2 + 1] = accy * inv;
  __syncthreads();
  if (tid < DD2) {
    float s = 0.f;
#pragma unroll
    for (int hh = 0; hh < H_HEADS; ++hh) s += hsum[hh][tid];
    out[(size_t)n * DD2 + tid] = f2bf(tanhf(s * 0.125f + bias[tid]));
  }
}

// ---------------- LSTM (single step, h0=c0=0) + FC ----------------
__global__ __launch_bounds__(128) void k_lstm(const float* __restrict__ gates,
                                              const float* __restrict__ b_ih,
                                              const float* __restrict__ b_hh,
                                              const float* __restrict__ fcW,
                                              const float* __restrict__ fcb,
                                              float* __restrict__ out) {
  int n = blockIdx.x;
  int j = threadIdx.x;
  __shared__ float gs[128];
  gs[j] = gates[(size_t)n * 128 + j] + b_ih[j] + b_hh[j];
  __syncthreads();
  if (j < 32) {
    float iv = gs[j], gv = gs[64 + j], ov = gs[96 + j];
    float c = (1.f / (1.f + __expf(-iv))) * tanhf(gv);
    float hd = (1.f / (1.f + __expf(-ov))) * tanhf(c);
    float p = hd * fcW[j];
#pragma unroll
    for (int off = 16; off > 0; off >>= 1) p += __shfl_down(p, off, 32);
    if (j == 0) out[n] = p + fcb[0];
  }
}

extern "C" void kernel_launch(void* const* d_in, const int* in_sizes, int n_in, void* d_out,
                              int out_size, void* d_ws, size_t ws_size, hipStream_t stream) {
  const float* x = (const float*)d_in[0];
  const int* ei = (const int*)d_in[1];
  const float* ea = (const float*)d_in[2];
  const float* Wl1 = (const float*)d_in[3];
  const float* Wr1 = (const float*)d_in[4];
  const float* We1 = (const float*)d_in[5];
  const float* att1 = (const float*)d_in[6];
  const float* b1 = (const float*)d_in[7];
  const float* Wl2 = (const float*)d_in[8];
  const float* Wr2 = (const float*)d_in[9];
  const float* We2 = (const float*)d_in[10];
  const float* att2 = (const float*)d_in[11];
  const float* b2 = (const float*)d_in[12];
  const float* W_ih = (const float*)d_in[13];
  const float* b_ih = (const float*)d_in[15];
  const float* b_hh = (const float*)d_in[16];
  const float* fcW = (const float*)d_in[17];
  const float* fcb = (const float*)d_in[18];
  float* out = (float*)d_out;
  const int* srcA = ei;
  const int* dstA = ei + N_EDGES;

  char* ws = (char*)d_ws;
  const size_t SZ_XL1 = (size_t)N_NODES * 512 * 2;
  const size_t SZ_P0 = (size_t)N_NODES * 1024 * 2;
  const size_t SZ_P1 = SZ_P0;
  const size_t SZ_H1 = (size_t)M_PAD * 512 * 2;
  const size_t SZ_H2 = (size_t)M_PAD * 128 * 2;
  size_t P0 = 0;
  size_t P1 = P0 + SZ_P0;
  size_t P2 = P1 + SZ_P1;
  size_t P3 = P2 + SZ_H1;
  size_t off = P3;
  auto take = [&](size_t bytes) -> char* {
    off = (off + 255) & ~(size_t)255;
    char* p = ws + off;
    off += bytes;
    return p;
  };
  u16* W1lT = (u16*)take((size_t)512 * K1_PAD * 2);
  u16* W1rT = (u16*)take((size_t)512 * K1_PAD * 2);
  u16* W2lT = (u16*)take((size_t)1024 * 512 * 2);
  u16* W2rT = (u16*)take((size_t)1024 * 512 * 2);
  u16* WihB = (u16*)take((size_t)128 * 128 * 2);
  int* deg = (int*)take((size_t)N_NODES * 4);
  int* cursor = (int*)take((size_t)N_NODES * 4);
  int* row_start = (int*)take((size_t)(N_NODES + 1) * 4);
  int* eid = (int*)take((size_t)N_EDGES * 4);
  int* srcp = (int*)take((size_t)N_EDGES * 4);

  if (off > ws_size) {
    k_zero<<<(out_size + 255) / 256, 256, 0, stream>>>(out, out_size);
    return;
  }

  u16* xl1 = (u16*)(ws + P0);
  u16* xr1 = (u16*)(ws + P0 + SZ_XL1);
  u16* xl2 = (u16*)(ws + P0);
  u16* xbf = (u16*)(ws + P1);
  u16* xr2 = (u16*)(ws + P1);
  u16* h1 = (u16*)(ws + P2);
  u16* h2 = (u16*)(ws + P2);
  float* gates = (float*)(ws + P2 + SZ_H2);

  hipMemsetAsync(deg, 0, (size_t)N_NODES * 4, stream);
  hipMemsetAsync(cursor, 0, (size_t)N_NODES * 4, stream);
  k_hist<<<(N_EDGES + 255) / 256, 256, 0, stream>>>(dstA, deg);
  k_scan<<<1, 1024, 0, stream>>>(deg, row_start);
  k_scatter<<<(N_EDGES + 255) / 256, 256, 0, stream>>>(dstA, srcA, row_start, cursor, eid, srcp);

  {
    long tot = (long)M_PAD * K1_PAD;
    k_cvt_x<<<(unsigned)((tot + 255) / 256), 256, 0, stream>>>(x, xbf);
    k_cvt_wT<<<(512 * K1_PAD + 255) / 256, 256, 0, stream>>>(Wl1, W1lT, F_INDIM, 512, K1_PAD);
    k_cvt_wT<<<(512 * K1_PAD + 255) / 256, 256, 0, stream>>>(Wr1, W1rT, F_INDIM, 512, K1_PAD);
    k_cvt_wT<<<(1024 * 512 + 255) / 256, 256, 0, stream>>>(Wl2, W2lT, 512, 1024, 512);
    k_cvt_wT<<<(1024 * 512 + 255) / 256, 256, 0, stream>>>(Wr2, W2rT, 512, 1024, 512);
    k_cvt<<<(128 * 128 + 255) / 256, 256, 0, stream>>>(W_ih, WihB, 128 * 128);
  }

  const int MB = M_PAD / 128;  // 391
  {
    dim3 g(512 / 128, MB);
    gemm_mfma<false><<<g, 256, 0, stream>>>(xbf, W1lT, xl1, N_NODES, 512, K1_PAD, K1_PAD, K1_PAD);
    gemm_mfma<false><<<g, 256, 0, stream>>>(xbf, W1rT, xr1, N_NODES, 512, K1_PAD, K1_PAD, K1_PAD);
  }
  k_gat1<<<N_NODES, 512, 0, stream>>>(xl1, xr1, ea, We1, att1, b1, srcp, eid, row_start, h1);

  {
    dim3 g(1024 / 128, MB);
    gemm_mfma<false><<<g, 256, 0, stream>>>(h1, W2lT, xl2, N_NODES, 1024, 512, 512, 512);
    gemm_mfma<false><<<g, 256, 0, stream>>>(h1, W2rT, xr2, N_NODES, 1024, 512, 512, 512);
  }
  k_gat2<<<N_NODES, 512, 0, stream>>>(xl2, xr2, ea, We2, att2, b2, srcp, eid, row_start, h2);

  {
    dim3 g(1, MB);
    gemm_mfma<true><<<g, 256, 0, stream>>>(h2, WihB, gates, N_NODES, 128, 128, 128, 128);
  }
  k_lstm<<<N_NODES, 128, 0, stream>>>(gates, b_ih, b_hh, fcW, fcb, out);
}